// Round 2
// baseline (1515.894 us; speedup 1.0000x reference)
//
#include <hip/hip_runtime.h>
#include <hip/hip_bf16.h>

#define BB 256
#define NN 2048
#define NSTEPS 64
#define DT_C 0.1f

typedef __attribute__((ext_vector_type(8))) short short8;
typedef __attribute__((ext_vector_type(4))) float floatx4;

__device__ __forceinline__ floatx4 mfma_bf16(short8 a, short8 b, floatx4 c) {
  return __builtin_amdgcn_mfma_f32_16x16x32_bf16(a, b, c, 0, 0, 0);
}

// Read one MFMA fragment (8 bf16 = 16B) from a 64-col LDS tile with XOR chunk swizzle.
__device__ __forceinline__ short8 fragread(const __hip_bfloat16* tile, int row, int kc) {
  return *(const short8*)(tile + row * 64 + ((kc ^ (row & 7)) << 3));
}

// One-time: convert f32 weight matrices to bf16 copies in workspace.
__global__ __launch_bounds__(256) void convert_kernel(
    const float* __restrict__ src, __hip_bfloat16* __restrict__ dst) {
  int i = (blockIdx.x * 256 + threadIdx.x) * 4;
  float4 v = *(const float4*)(src + i);
  dst[i + 0] = __float2bfloat16(v.x);
  dst[i + 1] = __float2bfloat16(v.y);
  dst[i + 2] = __float2bfloat16(v.z);
  dst[i + 3] = __float2bfloat16(v.w);
}

__global__ __launch_bounds__(256) void init_kernel(
    const float* __restrict__ x0,
    float* __restrict__ X, float* __restrict__ S, float* __restrict__ P,
    __hip_bfloat16* __restrict__ U, __hip_bfloat16* __restrict__ PSI) {
  int i = blockIdx.x * 256 + threadIdx.x;
  float v = x0[i];
  X[i] = v; S[i] = v; P[i] = v;
  float r = fmaxf(v, 0.f);
  U[i] = __float2bfloat16(r * r);   // u0 = relu(x0)*relu(x0)  (phi==g at t=0)
  PSI[i] = __float2bfloat16(r);
}

__global__ __launch_bounds__(256) void step_kernel(
    const __hip_bfloat16* __restrict__ Ww,
    const __hip_bfloat16* __restrict__ Tw,
    const float* __restrict__ Wb,
    const float* __restrict__ Tb,
    const float* __restrict__ wp2s,
    const float* __restrict__ ws2p,
    const float* __restrict__ fri,
    float* __restrict__ X, float* __restrict__ S, float* __restrict__ P,
    const __hip_bfloat16* __restrict__ Uin, const __hip_bfloat16* __restrict__ PSin,
    __hip_bfloat16* __restrict__ Uout, __hip_bfloat16* __restrict__ PSout,
    float* __restrict__ outX, float* __restrict__ outXS) {
  // LDS tiles (bf16): u 32x64 @0, psi 32x64 @2048, W 64x64 @4096, T 64x64 @8192
  __shared__ __align__(16) __hip_bfloat16 lds[12288];

  const int tid = threadIdx.x;
  const int lane = tid & 63, wv = tid >> 6;
  const int wr = wv >> 1, wc = wv & 1;
  const int row0 = (blockIdx.x >> 5) * 32;   // b-tile origin (8 tiles of 32)
  const int col0 = (blockIdx.x & 31) * 64;   // j-tile origin (32 tiles of 64)

  // ---- staging setup: 24 segments of 8 rows x 64 cols; 6 per wave ----
  const int lr = lane >> 3;  // row within segment (== row&7 of tile row)
  const int lc = lane & 7;   // stored chunk index
  const __hip_bfloat16* gsrc[6];
  int ldst[6];
#pragma unroll
  for (int i = 0; i < 6; ++i) {
    int seg = wv * 6 + i;
    const __hip_bfloat16* gb; int toff, sb, gr0;
    if (seg < 4)       { gb = Uin;  toff = 0;    sb = seg;      gr0 = row0; }
    else if (seg < 8)  { gb = PSin; toff = 2048; sb = seg - 4;  gr0 = row0; }
    else if (seg < 16) { gb = Ww;   toff = 4096; sb = seg - 8;  gr0 = col0; }
    else               { gb = Tw;   toff = 8192; sb = seg - 16; gr0 = col0; }
    int gr = gr0 + sb * 8 + lr;
    int cg = lc ^ lr;                       // swizzled global chunk
    gsrc[i] = gb + (size_t)gr * NN + cg * 8;
    ldst[i] = toff + (sb * 8 + lr) * 64 + lc * 8;
  }

  floatx4 accW[2] = {{0.f, 0.f, 0.f, 0.f}, {0.f, 0.f, 0.f, 0.f}};
  floatx4 accT[2] = {{0.f, 0.f, 0.f, 0.f}, {0.f, 0.f, 0.f, 0.f}};

  const int rowA = wr * 16 + (lane & 15);   // u/psi tile row (0..31)
  const int rowB = wc * 32 + (lane & 15);   // W/T tile row (0..63, +nf*16)
  const int kq = lane >> 4;                 // k-chunk group 0..3

  // prologue prefetch for it=0
  short8 stg[6];
#pragma unroll
  for (int i = 0; i < 6; ++i) stg[i] = *(const short8*)(gsrc[i]);

  for (int it = 0; it < NN / 64; ++it) {
    __syncthreads();                        // previous compute done; LDS reusable
#pragma unroll
    for (int i = 0; i < 6; ++i) *(short8*)(&lds[ldst[i]]) = stg[i];
    __syncthreads();
    if (it < NN / 64 - 1) {
      const int k0 = (it + 1) * 64;
#pragma unroll
      for (int i = 0; i < 6; ++i) stg[i] = *(const short8*)(gsrc[i] + k0);
    }
#pragma unroll
    for (int kb = 0; kb < 2; ++kb) {
      int kc = kb * 4 + kq;
      short8 au = fragread(&lds[0], rowA, kc);
      short8 ap = fragread(&lds[2048], rowA, kc);
#pragma unroll
      for (int nf = 0; nf < 2; ++nf) {
        short8 bw = fragread(&lds[4096], rowB + nf * 16, kc);
        short8 bt = fragread(&lds[8192], rowB + nf * 16, kc);
        accW[nf] = mfma_bf16(au, bw, accW[nf]);
        accT[nf] = mfma_bf16(ap, bt, accT[nf]);
      }
    }
  }

  // ---- fused epilogue: full state update + next-step operand production ----
  const int erow = row0 + wr * 16 + kq * 4;
#pragma unroll
  for (int nf = 0; nf < 2; ++nf) {
    int j = col0 + wc * 32 + nf * 16 + (lane & 15);
    float Wbj = Wb[j];
    float Tbj = Tb[j];
    float wpj = wp2s[j];
    float wsj = ws2p[j];
#pragma unroll
    for (int r = 0; r < 4; ++r) {
      int b = erow + r;
      size_t idx = (size_t)b * NN + j;
      float x = X[idx], s = S[idx], p = P[idx];
      float phi = fmaxf(x, 0.f), g = fmaxf(s, 0.f), psi = fmaxf(p, 0.f);
      float m1 = accW[nf][r], m2 = accT[nf][r];
      float fr = fri[idx];
      float xn = x + DT_C * (-x + m1 + Wbj) * fr;
      float sn = p + DT_C * (-s + wpj * psi + phi);   // note: base is p (as in source)
      float pn = p + DT_C * (-p + m2 + Tbj + wsj * g);
      X[idx] = xn; S[idx] = sn; P[idx] = pn;
      float phin = fmaxf(xn, 0.f);
      float gn = fmaxf(sn, 0.f);
      float psin = fmaxf(pn, 0.f);
      Uout[idx] = __float2bfloat16(phin * gn);
      PSout[idx] = __float2bfloat16(psin);
      outXS[idx] = xn;
      outX[idx] = xn;   // overwritten each step; after t=63 holds final x
    }
  }
}

extern "C" void kernel_launch(void* const* d_in, const int* in_sizes, int n_in,
                              void* d_out, int out_size, void* d_ws, size_t ws_size,
                              hipStream_t stream) {
  const float* x0   = (const float*)d_in[0];
  const float* fri  = (const float*)d_in[1];
  const float* Ww   = (const float*)d_in[2];
  const float* Wb   = (const float*)d_in[3];
  const float* Tw   = (const float*)d_in[4];
  const float* Tb   = (const float*)d_in[5];
  const float* wp2s = (const float*)d_in[6];
  const float* ws2p = (const float*)d_in[7];
  float* out = (float*)d_out;

  const size_t BN = (size_t)BB * NN;
  const size_t NW = (size_t)NN * NN;
  float* X = (float*)d_ws;
  float* S = X + BN;
  float* P = S + BN;
  __hip_bfloat16* U0  = (__hip_bfloat16*)(P + BN);
  __hip_bfloat16* PS0 = U0 + BN;
  __hip_bfloat16* U1  = PS0 + BN;
  __hip_bfloat16* PS1 = U1 + BN;
  __hip_bfloat16* Wbf = PS1 + BN;
  __hip_bfloat16* Tbf = Wbf + NW;

  convert_kernel<<<(int)(NW / 1024), 256, 0, stream>>>(Ww, Wbf);
  convert_kernel<<<(int)(NW / 1024), 256, 0, stream>>>(Tw, Tbf);
  init_kernel<<<(int)(BN / 256), 256, 0, stream>>>(x0, X, S, P, U0, PS0);

  for (int t = 0; t < NSTEPS; ++t) {
    const __hip_bfloat16* Uin  = (t & 1) ? U1 : U0;
    const __hip_bfloat16* PSin = (t & 1) ? PS1 : PS0;
    __hip_bfloat16* Uout  = (t & 1) ? U0 : U1;
    __hip_bfloat16* PSout = (t & 1) ? PS0 : PS1;
    float* outXS = out + BN + (size_t)t * BN;
    step_kernel<<<256, 256, 0, stream>>>(Wbf, Tbf, Wb, Tb, wp2s, ws2p, fri,
                                         X, S, P, Uin, PSin, Uout, PSout,
                                         out, outXS);
  }
}

// Round 3
// 1390.590 us; speedup vs baseline: 1.0901x; 1.0901x over previous
//
#include <hip/hip_runtime.h>
#include <hip/hip_bf16.h>

#define BB 256
#define NN 2048
#define NSTEPS 64
#define DT_C 0.1f

typedef __attribute__((ext_vector_type(8))) short short8;
typedef __attribute__((ext_vector_type(4))) float floatx4;

__device__ __forceinline__ floatx4 mfma_bf16(short8 a, short8 b, floatx4 c) {
  return __builtin_amdgcn_mfma_f32_16x16x32_bf16(a, b, c, 0, 0, 0);
}

// Read one MFMA fragment (16B) from a 64-col LDS tile with XOR chunk swizzle.
__device__ __forceinline__ short8 fragread(const __hip_bfloat16* tile, int row, int kc) {
  return *(const short8*)(tile + row * 64 + ((kc ^ (row & 7)) << 3));
}

// Async global->LDS, 16B per lane. LDS dest is wave-uniform base + lane*16.
__device__ __forceinline__ void gl_lds16(const __hip_bfloat16* g, __hip_bfloat16* l) {
  __builtin_amdgcn_global_load_lds(
      (const __attribute__((address_space(1))) unsigned int*)g,
      (__attribute__((address_space(3))) unsigned int*)l, 16, 0, 0);
}

// One-time: convert f32 weight matrices to bf16 copies in workspace.
__global__ __launch_bounds__(256) void convert_kernel(
    const float* __restrict__ src, __hip_bfloat16* __restrict__ dst) {
  int i = (blockIdx.x * 256 + threadIdx.x) * 4;
  float4 v = *(const float4*)(src + i);
  dst[i + 0] = __float2bfloat16(v.x);
  dst[i + 1] = __float2bfloat16(v.y);
  dst[i + 2] = __float2bfloat16(v.z);
  dst[i + 3] = __float2bfloat16(v.w);
}

__global__ __launch_bounds__(256) void init_kernel(
    const float* __restrict__ x0,
    __hip_bfloat16* __restrict__ U, __hip_bfloat16* __restrict__ PSI) {
  int i = blockIdx.x * 256 + threadIdx.x;
  float r = fmaxf(x0[i], 0.f);
  U[i] = __float2bfloat16(r * r);   // u0 = relu(x0)*relu(x0) (phi==g at t=0)
  PSI[i] = __float2bfloat16(r);
}

// Block tile: 64 batch rows x 32 output cols, BOTH GEMMs. 8 waves:
// waves 0-3 -> W-GEMM (A=U), waves 4-7 -> T-GEMM (A=PSI); wave wv&3 owns rows wr*16..+15.
__global__ __launch_bounds__(512) void step_kernel(
    const __hip_bfloat16* __restrict__ Wbf, const __hip_bfloat16* __restrict__ Tbf,
    const float* __restrict__ Wb, const float* __restrict__ Tb,
    const float* __restrict__ wp2s, const float* __restrict__ ws2p,
    const float* __restrict__ fri,
    const float* __restrict__ Xprev, const float* Sprev, const float* Pprev,
    const __hip_bfloat16* __restrict__ Uprev, const __hip_bfloat16* __restrict__ PSprev,
    float* Snew, float* Pnew,
    __hip_bfloat16* __restrict__ Unew, __hip_bfloat16* __restrict__ PSnew,
    float* __restrict__ xsout, float* __restrict__ outFin, int last) {
  // per buffer (bf16 elems): U[64][64]@0, PSI@4096, Wsl[32][64]@8192, Tsl@10240
  __shared__ __align__(16) __hip_bfloat16 lds[2][12288];  // 48 KB

  const int tid = threadIdx.x;
  const int lane = tid & 63, wv = tid >> 6;
  const int lane15 = lane & 15, kq = lane >> 4;
  const bool isW = wv < 4;
  const int wr = wv & 3;

  // XCD-aware bijective swizzle: blocks with same bid%8 (same XCD) get
  // 8 consecutive column tiles x all 4 row tiles -> 2MB weights per XCD L2.
  const int sb = ((blockIdx.x & 7) << 5) + (blockIdx.x >> 3);
  const int col = sb >> 2, rowt = sb & 3;
  const int b0 = rowt * 64, j0 = col * 32;

  // staging: 24 segments of (8 rows x 64 k) = 1KB each; 3 per wave.
  // LDS slot for lane: row=lane>>3, chunk=lane&7 (linear); global source is
  // pre-swizzled: chunk_src = (lane&7) ^ (lane>>3), so read-side uses kc^(row&7).
  const __hip_bfloat16* gsrc[3];
  int ldso[3];
#pragma unroll
  for (int i = 0; i < 3; ++i) {
    int seg = wv * 3 + i;
    const __hip_bfloat16* arr; int g0, lo;
    if (seg < 8)       { arr = Uprev;  g0 = b0 + seg * 8;        lo = seg * 512; }
    else if (seg < 16) { arr = PSprev; g0 = b0 + (seg - 8) * 8;  lo = 4096 + (seg - 8) * 512; }
    else if (seg < 20) { arr = Wbf;    g0 = j0 + (seg - 16) * 8; lo = 8192 + (seg - 16) * 512; }
    else               { arr = Tbf;    g0 = j0 + (seg - 20) * 8; lo = 10240 + (seg - 20) * 512; }
    const int lr = lane >> 3;
    const int ch = (lane & 7) ^ lr;
    gsrc[i] = arr + (size_t)(g0 + lr) * NN + ch * 8;
    ldso[i] = lo;
  }

  floatx4 acc[2] = {{0.f, 0.f, 0.f, 0.f}, {0.f, 0.f, 0.f, 0.f}};
  const int rowA = wr * 16 + lane15;

  // prologue: stage kt=0 into buf0
#pragma unroll
  for (int i = 0; i < 3; ++i) gl_lds16(gsrc[i], &lds[0][ldso[i]]);
  __syncthreads();

  for (int kt = 0; kt < NN / 64; ++kt) {
    const int cur = kt & 1;
    if (kt < NN / 64 - 1) {
#pragma unroll
      for (int i = 0; i < 3; ++i)
        gl_lds16(gsrc[i] + (kt + 1) * 64, &lds[cur ^ 1][ldso[i]]);
    }
    const __hip_bfloat16* Ab = &lds[cur][isW ? 0 : 4096];
    const __hip_bfloat16* Bb = &lds[cur][isW ? 8192 : 10240];
#pragma unroll
    for (int kb = 0; kb < 2; ++kb) {
      const int kc = kb * 4 + kq;
      short8 a = fragread(Ab, rowA, kc);
      short8 bf0 = fragread(Bb, lane15, kc);
      short8 bf1 = fragread(Bb, lane15 + 16, kc);
      acc[0] = mfma_bf16(a, bf0, acc[0]);
      acc[1] = mfma_bf16(a, bf1, acc[1]);
    }
    __syncthreads();
  }

  // T-waves publish m2 tile via LDS (padded stride 33 to dodge bank conflicts)
  float* eb = (float*)&lds[0][0];
  if (!isW) {
#pragma unroll
    for (int nf = 0; nf < 2; ++nf)
#pragma unroll
      for (int r = 0; r < 4; ++r)
        eb[(wr * 16 + kq * 4 + r) * 33 + nf * 16 + lane15] = acc[nf][r];
  }
  __syncthreads();

  if (isW) {
#pragma unroll
    for (int nf = 0; nf < 2; ++nf) {
      const int j = j0 + nf * 16 + lane15;
      const float Wbj = Wb[j], Tbj = Tb[j], wpj = wp2s[j], wsj = ws2p[j];
#pragma unroll
      for (int r = 0; r < 4; ++r) {
        const int row = wr * 16 + kq * 4 + r;
        const int b = b0 + row;
        const size_t idx = (size_t)b * NN + j;
        const float m1 = acc[nf][r];
        const float m2 = eb[row * 33 + nf * 16 + lane15];
        const float x = Xprev[idx], s = Sprev[idx], p = Pprev[idx];
        const float fr = fri[idx];
        const float phi = fmaxf(x, 0.f), g = fmaxf(s, 0.f), psi = fmaxf(p, 0.f);
        const float xn = x + DT_C * (-x + m1 + Wbj) * fr;
        const float sn = p + DT_C * (-s + wpj * psi + phi);  // base is p (as in source)
        const float pn = p + DT_C * (-p + m2 + Tbj + wsj * g);
        Snew[idx] = sn;
        Pnew[idx] = pn;
        xsout[idx] = xn;
        if (last) outFin[idx] = xn;
        Unew[idx] = __float2bfloat16(fmaxf(xn, 0.f) * fmaxf(sn, 0.f));
        PSnew[idx] = __float2bfloat16(fmaxf(pn, 0.f));
      }
    }
  }
}

extern "C" void kernel_launch(void* const* d_in, const int* in_sizes, int n_in,
                              void* d_out, int out_size, void* d_ws, size_t ws_size,
                              hipStream_t stream) {
  const float* x0   = (const float*)d_in[0];
  const float* fri  = (const float*)d_in[1];
  const float* Ww   = (const float*)d_in[2];
  const float* Wb   = (const float*)d_in[3];
  const float* Tw   = (const float*)d_in[4];
  const float* Tb   = (const float*)d_in[5];
  const float* wp2s = (const float*)d_in[6];
  const float* ws2p = (const float*)d_in[7];
  float* out = (float*)d_out;

  const size_t BN = (size_t)BB * NN;
  const size_t NW = (size_t)NN * NN;
  float* S = (float*)d_ws;                      // single-buffer (owner-exclusive idx)
  float* P = S + BN;
  __hip_bfloat16* U0  = (__hip_bfloat16*)(P + BN);
  __hip_bfloat16* U1  = U0 + BN;
  __hip_bfloat16* PS0 = U1 + BN;
  __hip_bfloat16* PS1 = PS0 + BN;
  __hip_bfloat16* Wbf = PS1 + BN;
  __hip_bfloat16* Tbf = Wbf + NW;

  convert_kernel<<<(int)(NW / 1024), 256, 0, stream>>>(Ww, Wbf);
  convert_kernel<<<(int)(NW / 1024), 256, 0, stream>>>(Tw, Tbf);
  init_kernel<<<(int)(BN / 256), 256, 0, stream>>>(x0, U0, PS0);

  float* xs = out + BN;  // xs[t] = out + BN + t*BN
  for (int t = 0; t < NSTEPS; ++t) {
    const float* Xprev = (t == 0) ? x0 : (xs + (size_t)(t - 1) * BN);
    const float* Sprev = (t == 0) ? x0 : S;
    const float* Pprev = (t == 0) ? x0 : P;
    const __hip_bfloat16* Uprev  = (t & 1) ? U1 : U0;
    const __hip_bfloat16* PSprev = (t & 1) ? PS1 : PS0;
    __hip_bfloat16* Unew  = (t & 1) ? U0 : U1;
    __hip_bfloat16* PSnew = (t & 1) ? PS0 : PS1;
    step_kernel<<<256, 512, 0, stream>>>(Wbf, Tbf, Wb, Tb, wp2s, ws2p, fri,
                                         Xprev, Sprev, Pprev, Uprev, PSprev,
                                         S, P, Unew, PSnew,
                                         xs + (size_t)t * BN, out,
                                         (t == NSTEPS - 1) ? 1 : 0);
  }
}

// Round 4
// 1076.177 us; speedup vs baseline: 1.4086x; 1.2922x over previous
//
#include <hip/hip_runtime.h>
#include <hip/hip_bf16.h>

#define BB 256
#define NN 2048
#define NSTEPS 64
#define DT_C 0.1f

typedef __attribute__((ext_vector_type(8))) short short8;
typedef __attribute__((ext_vector_type(4))) float floatx4;

__device__ __forceinline__ floatx4 mfma_bf16(short8 a, short8 b, floatx4 c) {
  return __builtin_amdgcn_mfma_f32_16x16x32_bf16(a, b, c, 0, 0, 0);
}

__device__ __forceinline__ short bf16bits(float f) {
  __hip_bfloat16 h = __float2bfloat16(f);
  return *reinterpret_cast<short*>(&h);
}

// ---------------- fragment-major layouts ----------------
// A-matrices (U/PSI, 256x2048): frag(rf=row>>4, kc=k>>5), frag idx = rf*64+kc,
//   512 bf16 per frag; in-frag: lane = (row&15) | (((k>>3)&3)<<4), elem = k&7,
//   offset = lane*8 + elem.  One frag = 1KB contiguous = one dwordx4 wave load.
// B-matrices (W/T, NxN; "row" j = output col): frag(cf=j>>4, kc=k>>5),
//   frag idx = cf*64+kc, same in-frag layout with row->j.

// one-time: f32 row-major NxN -> bf16 fragment-major (one thread per 16B chunk)
__global__ __launch_bounds__(256) void convert_kernel(
    const float* __restrict__ src, __hip_bfloat16* __restrict__ dst) {
  const int g = blockIdx.x * 256 + threadIdx.x;
  const int frag = g >> 6, l = g & 63;
  const int j = (frag >> 6) * 16 + (l & 15);
  const int k = (frag & 63) * 32 + (l >> 4) * 8;
  const float* s = src + (size_t)j * NN + k;
  short8 v;
#pragma unroll
  for (int e = 0; e < 8; ++e) v[e] = bf16bits(s[e]);
  *(short8*)((short*)dst + (size_t)g * 8) = v;
}

__global__ __launch_bounds__(256) void init_kernel(
    const float* __restrict__ x0,
    __hip_bfloat16* __restrict__ U, __hip_bfloat16* __restrict__ PSI) {
  const int i = blockIdx.x * 256 + threadIdx.x;
  const int b = i >> 11, j = i & (NN - 1);
  const float r = fmaxf(x0[i], 0.f);
  const int dl = (b & 15) | (((j >> 3) & 3) << 4);
  const size_t fo = ((size_t)((b >> 4) * 64 + (j >> 5))) * 512 + dl * 8 + (j & 7);
  U[fo] = __float2bfloat16(r * r);   // u0 = relu(x0)*relu(x0)  (phi==g at t=0)
  PSI[fo] = __float2bfloat16(r);
}

// Block: 64 batch rows x 32 output cols, BOTH GEMMs. 8 waves:
// waves 0-3 -> W-GEMM (A=U), waves 4-7 -> T-GEMM (A=PSI); wave owns 16 rows x 32 cols.
// K-loop is LDS-free: fragment loads go global->VGPR (all frags contiguous 1KB).
__global__ __launch_bounds__(512) void step_kernel(
    const __hip_bfloat16* __restrict__ Wf, const __hip_bfloat16* __restrict__ Tf,
    const float* __restrict__ Wb, const float* __restrict__ Tb,
    const float* __restrict__ wp2s, const float* __restrict__ ws2p,
    const float* __restrict__ fri,
    const float* __restrict__ Xprev, const float* __restrict__ Sprev,
    const float* __restrict__ Pprev,
    const __hip_bfloat16* __restrict__ Uprev, const __hip_bfloat16* __restrict__ PSprev,
    float* __restrict__ Snew, float* __restrict__ Pnew,
    __hip_bfloat16* __restrict__ Unew, __hip_bfloat16* __restrict__ PSnew,
    float* __restrict__ xsout, float* __restrict__ outFin, int last) {
  __shared__ __align__(16) float eb[64 * 33];   // m2 exchange (T-waves -> W-waves)

  const int tid = threadIdx.x;
  const int lane = tid & 63, wv = tid >> 6;
  const int lane15 = lane & 15, kq = lane >> 4;
  const bool isW = wv < 4;
  const int wr = wv & 3;

  // XCD-aware bijective swizzle: same-XCD blocks share weight/activation panels in L2.
  const int sb = ((blockIdx.x & 7) << 5) + (blockIdx.x >> 3);
  const int col = sb >> 2, rowt = sb & 3;
  const int b0 = rowt * 64, j0 = col * 32;

  const short* Af = (const short*)(isW ? Uprev : PSprev);
  const short* Bf = (const short*)(isW ? Wf : Tf);
  const int rf = rowt * 4 + wr;    // A row-fragment index (16 rows)
  const int cf0 = col * 2;         // B col-fragment index (2 x 16 cols)

  const short* aP  = Af + ((size_t)rf * 64) * 512 + lane * 8;
  const short* b0P = Bf + ((size_t)cf0 * 64) * 512 + lane * 8;
  const short* b1P = Bf + ((size_t)(cf0 + 1) * 64) * 512 + lane * 8;

  floatx4 acc[2] = {{0.f, 0.f, 0.f, 0.f}, {0.f, 0.f, 0.f, 0.f}};

  // depth-2 software pipeline, no barriers -> counted vmcnt, deep overlap
  short8 a0 = *(const short8*)(aP);
  short8 c0 = *(const short8*)(b0P);
  short8 d0 = *(const short8*)(b1P);
  short8 a1 = *(const short8*)(aP + 512);
  short8 c1 = *(const short8*)(b0P + 512);
  short8 d1 = *(const short8*)(b1P + 512);

  for (int kc = 0; kc < 62; kc += 2) {
    short8 na0 = *(const short8*)(aP + (size_t)(kc + 2) * 512);
    short8 nc0 = *(const short8*)(b0P + (size_t)(kc + 2) * 512);
    short8 nd0 = *(const short8*)(b1P + (size_t)(kc + 2) * 512);
    short8 na1 = *(const short8*)(aP + (size_t)(kc + 3) * 512);
    short8 nc1 = *(const short8*)(b0P + (size_t)(kc + 3) * 512);
    short8 nd1 = *(const short8*)(b1P + (size_t)(kc + 3) * 512);
    acc[0] = mfma_bf16(a0, c0, acc[0]);
    acc[1] = mfma_bf16(a0, d0, acc[1]);
    acc[0] = mfma_bf16(a1, c1, acc[0]);
    acc[1] = mfma_bf16(a1, d1, acc[1]);
    a0 = na0; c0 = nc0; d0 = nd0;
    a1 = na1; c1 = nc1; d1 = nd1;
  }
  acc[0] = mfma_bf16(a0, c0, acc[0]);
  acc[1] = mfma_bf16(a0, d0, acc[1]);
  acc[0] = mfma_bf16(a1, c1, acc[0]);
  acc[1] = mfma_bf16(a1, d1, acc[1]);

  // T-waves publish m2 tile (padded stride 33: conflict-free)
  if (!isW) {
#pragma unroll
    for (int nf = 0; nf < 2; ++nf)
#pragma unroll
      for (int r = 0; r < 4; ++r)
        eb[(wr * 16 + kq * 4 + r) * 33 + nf * 16 + lane15] = acc[nf][r];
  }
  __syncthreads();

  if (isW) {
#pragma unroll
    for (int nf = 0; nf < 2; ++nf) {
      const int j = j0 + nf * 16 + lane15;
      const float Wbj = Wb[j], Tbj = Tb[j], wpj = wp2s[j], wsj = ws2p[j];
#pragma unroll
      for (int r = 0; r < 4; ++r) {
        const int row = wr * 16 + kq * 4 + r;
        const int b = b0 + row;
        const size_t idx = (size_t)b * NN + j;
        const float m1 = acc[nf][r];
        const float m2 = eb[row * 33 + nf * 16 + lane15];
        const float x = Xprev[idx], s = Sprev[idx], p = Pprev[idx];
        const float fr = fri[idx];
        const float phi = fmaxf(x, 0.f), g = fmaxf(s, 0.f), psi = fmaxf(p, 0.f);
        const float xn = x + DT_C * (-x + m1 + Wbj) * fr;
        const float sn = p + DT_C * (-s + wpj * psi + phi);  // base is p (as in source)
        const float pn = p + DT_C * (-p + m2 + Tbj + wsj * g);
        Snew[idx] = sn;
        Pnew[idx] = pn;
        xsout[idx] = xn;
        if (last) outFin[idx] = xn;
        // next-step operands, fragment-major
        const int dl = (kq * 4 + r) | ((nf * 2 + (lane15 >> 3)) << 4);
        const size_t fo = ((size_t)rf * 64 + col) * 512 + dl * 8 + (lane15 & 7);
        Unew[fo] = __float2bfloat16(fmaxf(xn, 0.f) * fmaxf(sn, 0.f));
        PSnew[fo] = __float2bfloat16(fmaxf(pn, 0.f));
      }
    }
  }
}

extern "C" void kernel_launch(void* const* d_in, const int* in_sizes, int n_in,
                              void* d_out, int out_size, void* d_ws, size_t ws_size,
                              hipStream_t stream) {
  const float* x0   = (const float*)d_in[0];
  const float* fri  = (const float*)d_in[1];
  const float* Ww   = (const float*)d_in[2];
  const float* Wb   = (const float*)d_in[3];
  const float* Tw   = (const float*)d_in[4];
  const float* Tb   = (const float*)d_in[5];
  const float* wp2s = (const float*)d_in[6];
  const float* ws2p = (const float*)d_in[7];
  float* out = (float*)d_out;

  const size_t BN = (size_t)BB * NN;
  const size_t NW = (size_t)NN * NN;
  float* S = (float*)d_ws;
  float* P = S + BN;
  __hip_bfloat16* U0  = (__hip_bfloat16*)(P + BN);
  __hip_bfloat16* U1  = U0 + BN;
  __hip_bfloat16* PS0 = U1 + BN;
  __hip_bfloat16* PS1 = PS0 + BN;
  __hip_bfloat16* Wf  = PS1 + BN;
  __hip_bfloat16* Tf  = Wf + NW;

  convert_kernel<<<(int)(NW / 2048), 256, 0, stream>>>(Ww, Wf);
  convert_kernel<<<(int)(NW / 2048), 256, 0, stream>>>(Tw, Tf);
  init_kernel<<<(int)(BN / 256), 256, 0, stream>>>(x0, U0, PS0);

  float* xs = out + BN;  // xs[t] = out + BN + t*BN
  for (int t = 0; t < NSTEPS; ++t) {
    const float* Xprev = (t == 0) ? x0 : (xs + (size_t)(t - 1) * BN);
    const float* Sprev = (t == 0) ? x0 : S;
    const float* Pprev = (t == 0) ? x0 : P;
    const __hip_bfloat16* Uprev  = (t & 1) ? U1 : U0;
    const __hip_bfloat16* PSprev = (t & 1) ? PS1 : PS0;
    __hip_bfloat16* Unew  = (t & 1) ? U0 : U1;
    __hip_bfloat16* PSnew = (t & 1) ? PS0 : PS1;
    step_kernel<<<256, 512, 0, stream>>>(Wf, Tf, Wb, Tb, wp2s, ws2p, fri,
                                         Xprev, Sprev, Pprev, Uprev, PSprev,
                                         S, P, Unew, PSnew,
                                         xs + (size_t)t * BN, out,
                                         (t == NSTEPS - 1) ? 1 : 0);
  }
}

// Round 5
// 1054.330 us; speedup vs baseline: 1.4378x; 1.0207x over previous
//
#include <hip/hip_runtime.h>
#include <hip/hip_bf16.h>

#define BB 256
#define NN 2048
#define NSTEPS 64
#define DT_C 0.1f

typedef __attribute__((ext_vector_type(8))) short short8;
typedef __attribute__((ext_vector_type(4))) float floatx4;

__device__ __forceinline__ floatx4 mfma_bf16(short8 a, short8 b, floatx4 c) {
  return __builtin_amdgcn_mfma_f32_16x16x32_bf16(a, b, c, 0, 0, 0);
}

__device__ __forceinline__ short bf16bits(float f) {
  __hip_bfloat16 h = __float2bfloat16(f);
  return *reinterpret_cast<short*>(&h);
}

// ---------------- fragment-major layouts (as round 4, verified) ----------------
// frag(rf=row>>4, kc=k>>5), frag idx = rf*64+kc, 512 bf16/frag (1KB contiguous);
// in-frag: lane = (row&15) | (((k>>3)&3)<<4), elem = k&7.

__global__ __launch_bounds__(256) void convert_kernel(
    const float* __restrict__ src, __hip_bfloat16* __restrict__ dst) {
  const int g = blockIdx.x * 256 + threadIdx.x;
  const int frag = g >> 6, l = g & 63;
  const int j = (frag >> 6) * 16 + (l & 15);
  const int k = (frag & 63) * 32 + (l >> 4) * 8;
  const float* s = src + (size_t)j * NN + k;
  short8 v;
#pragma unroll
  for (int e = 0; e < 8; ++e) v[e] = bf16bits(s[e]);
  *(short8*)((short*)dst + (size_t)g * 8) = v;
}

__global__ __launch_bounds__(256) void init_kernel(
    const float* __restrict__ x0,
    __hip_bfloat16* __restrict__ U, __hip_bfloat16* __restrict__ PSI) {
  const int i = blockIdx.x * 256 + threadIdx.x;
  const int b = i >> 11, j = i & (NN - 1);
  const float r = fmaxf(x0[i], 0.f);
  const int dl = (b & 15) | (((j >> 3) & 3) << 4);
  const size_t fo = ((size_t)((b >> 4) * 64 + (j >> 5))) * 512 + dl * 8 + (j & 7);
  U[fo] = __float2bfloat16(r * r);   // u0 = relu(x0)*relu(x0)  (phi==g at t=0)
  PSI[fo] = __float2bfloat16(r);
}

#define LOADST(S, kc) \
  S##a0 = *(const short8*)(aP0 + (size_t)(kc) * 512); \
  S##a1 = *(const short8*)(aP1 + (size_t)(kc) * 512); \
  S##b0 = *(const short8*)(bP0 + (size_t)(kc) * 512); \
  S##b1 = *(const short8*)(bP1 + (size_t)(kc) * 512);
#define DOMFMA(S) \
  acc00 = mfma_bf16(S##a0, S##b0, acc00); \
  acc01 = mfma_bf16(S##a0, S##b1, acc01); \
  acc10 = mfma_bf16(S##a1, S##b0, acc10); \
  acc11 = mfma_bf16(S##a1, S##b1, acc11);

// Block: 64 rows x 32 cols, BOTH GEMMs. 8 waves: wv = g*4 + rw*2 + h
//   g: 0=W-GEMM(A=U), 1=T-GEMM(A=PSI); rw: row-half (32 rows); h: K-half (1024).
// Every wave's 4 global streams are disjoint -> zero redundant VMEM traffic.
__global__ __launch_bounds__(512) void step_kernel(
    const __hip_bfloat16* __restrict__ Wf, const __hip_bfloat16* __restrict__ Tf,
    const float* __restrict__ Wb, const float* __restrict__ Tb,
    const float* __restrict__ wp2s, const float* __restrict__ ws2p,
    const float* __restrict__ fri,
    const float* __restrict__ Xprev, const float* __restrict__ Sprev,
    const float* __restrict__ Pprev,
    const __hip_bfloat16* __restrict__ Uprev, const __hip_bfloat16* __restrict__ PSprev,
    float* __restrict__ Snew, float* __restrict__ Pnew,
    __hip_bfloat16* __restrict__ Unew, __hip_bfloat16* __restrict__ PSnew,
    float* __restrict__ xsout, float* __restrict__ outFin, int last) {
  __shared__ float eb[8][32][36];   // per-wave 32x32 f32 partials, padded (36.9KB)

  const int tid = threadIdx.x;
  const int lane = tid & 63, wv = tid >> 6;
  const int lane15 = lane & 15, kq = lane >> 4;
  const int g = wv >> 2, rw = (wv >> 1) & 1, h = wv & 1;

  // XCD-aware bijective swizzle: XCD x owns col-tiles x*8..x*8+7 (2MB weights in L2).
  const int x = blockIdx.x & 7, ii = blockIdx.x >> 3;
  const int colt = x * 8 + (ii >> 2), rowt = ii & 3;
  const int b0 = rowt * 64, j0 = colt * 32;

  const short* Af = (const short*)(g == 0 ? Uprev : PSprev);
  const short* Bf = (const short*)(g == 0 ? Wf : Tf);
  const int rf0 = rowt * 4 + rw * 2;   // A row-frag base (rows rw*32..+31)
  const int cf0 = colt * 2;            // B col-frag base (cols j0..+31)
  const int kcb = h * 32;              // K-half base (frag-k units)

  const short* aP0 = Af + ((size_t)rf0 * 64 + kcb) * 512 + lane * 8;
  const short* aP1 = Af + ((size_t)(rf0 + 1) * 64 + kcb) * 512 + lane * 8;
  const short* bP0 = Bf + ((size_t)cf0 * 64 + kcb) * 512 + lane * 8;
  const short* bP1 = Bf + ((size_t)(cf0 + 1) * 64 + kcb) * 512 + lane * 8;

  floatx4 acc00 = {0.f, 0.f, 0.f, 0.f}, acc01 = {0.f, 0.f, 0.f, 0.f};
  floatx4 acc10 = {0.f, 0.f, 0.f, 0.f}, acc11 = {0.f, 0.f, 0.f, 0.f};

  short8 Aa0, Aa1, Ab0, Ab1, Ba0, Ba1, Bb0, Bb1, Ca0, Ca1, Cb0, Cb1;
  LOADST(A, 0) LOADST(B, 1) LOADST(C, 2)
  for (int kc = 0; kc < 27; kc += 3) {   // 9 triples: process 0..26, load 3..29
    DOMFMA(A) LOADST(A, kc + 3)
    DOMFMA(B) LOADST(B, kc + 4)
    DOMFMA(C) LOADST(C, kc + 5)
  }
  DOMFMA(A) LOADST(A, 30)
  DOMFMA(B) LOADST(B, 31)
  DOMFMA(C) DOMFMA(A) DOMFMA(B)          // 27 + 5 = 32 iters, no OOB loads

  // publish partials: eb[wv][local row][local col]
#pragma unroll
  for (int r = 0; r < 4; ++r) {
    eb[wv][0 * 16 + kq * 4 + r][0 * 16 + lane15] = acc00[r];
    eb[wv][0 * 16 + kq * 4 + r][1 * 16 + lane15] = acc01[r];
    eb[wv][1 * 16 + kq * 4 + r][0 * 16 + lane15] = acc10[r];
    eb[wv][1 * 16 + kq * 4 + r][1 * 16 + lane15] = acc11[r];
  }
  __syncthreads();

  // fused epilogue: all 512 threads, 4 elements each
  const int c = tid & 31, r4 = tid >> 5;   // r4: 0..15
  const int j = j0 + c;
  const float Wbj = Wb[j], Tbj = Tb[j], wpj = wp2s[j], wsj = ws2p[j];
#pragma unroll
  for (int i = 0; i < 4; ++i) {
    const int r = r4 * 4 + i;              // 0..63
    const int rh = r >> 5, rl = r & 31;
    const float m1 = eb[rh * 2 + 0][rl][c] + eb[rh * 2 + 1][rl][c];
    const float m2 = eb[4 + rh * 2 + 0][rl][c] + eb[4 + rh * 2 + 1][rl][c];
    const int b = b0 + r;
    const size_t idx = (size_t)b * NN + j;
    const float xv = Xprev[idx], s = Sprev[idx], p = Pprev[idx];
    const float fr = fri[idx];
    const float phi = fmaxf(xv, 0.f), gg = fmaxf(s, 0.f), psi = fmaxf(p, 0.f);
    const float xn = xv + DT_C * (-xv + m1 + Wbj) * fr;
    const float sn = p + DT_C * (-s + wpj * psi + phi);   // base is p (as in source)
    const float pn = p + DT_C * (-p + m2 + Tbj + wsj * gg);
    Snew[idx] = sn;
    Pnew[idx] = pn;
    xsout[idx] = xn;
    if (last) outFin[idx] = xn;
    // next-step operands, fragment-major
    const int dl = (b & 15) | (((j >> 3) & 3) << 4);
    const size_t fo = ((size_t)((b >> 4) * 64 + (j >> 5))) * 512 + dl * 8 + (j & 7);
    Unew[fo] = __float2bfloat16(fmaxf(xn, 0.f) * fmaxf(sn, 0.f));
    PSnew[fo] = __float2bfloat16(fmaxf(pn, 0.f));
  }
}

extern "C" void kernel_launch(void* const* d_in, const int* in_sizes, int n_in,
                              void* d_out, int out_size, void* d_ws, size_t ws_size,
                              hipStream_t stream) {
  const float* x0   = (const float*)d_in[0];
  const float* fri  = (const float*)d_in[1];
  const float* Ww   = (const float*)d_in[2];
  const float* Wb   = (const float*)d_in[3];
  const float* Tw   = (const float*)d_in[4];
  const float* Tb   = (const float*)d_in[5];
  const float* wp2s = (const float*)d_in[6];
  const float* ws2p = (const float*)d_in[7];
  float* out = (float*)d_out;

  const size_t BN = (size_t)BB * NN;
  const size_t NW = (size_t)NN * NN;
  float* S = (float*)d_ws;
  float* P = S + BN;
  __hip_bfloat16* U0  = (__hip_bfloat16*)(P + BN);
  __hip_bfloat16* U1  = U0 + BN;
  __hip_bfloat16* PS0 = U1 + BN;
  __hip_bfloat16* PS1 = PS0 + BN;
  __hip_bfloat16* Wf  = PS1 + BN;
  __hip_bfloat16* Tf  = Wf + NW;

  convert_kernel<<<(int)(NW / 2048), 256, 0, stream>>>(Ww, Wf);
  convert_kernel<<<(int)(NW / 2048), 256, 0, stream>>>(Tw, Tf);
  init_kernel<<<(int)(BN / 256), 256, 0, stream>>>(x0, U0, PS0);

  float* xs = out + BN;  // xs[t] = out + BN + t*BN
  for (int t = 0; t < NSTEPS; ++t) {
    const float* Xprev = (t == 0) ? x0 : (xs + (size_t)(t - 1) * BN);
    const float* Sprev = (t == 0) ? x0 : S;
    const float* Pprev = (t == 0) ? x0 : P;
    const __hip_bfloat16* Uprev  = (t & 1) ? U1 : U0;
    const __hip_bfloat16* PSprev = (t & 1) ? PS1 : PS0;
    __hip_bfloat16* Unew  = (t & 1) ? U0 : U1;
    __hip_bfloat16* PSnew = (t & 1) ? PS0 : PS1;
    step_kernel<<<256, 512, 0, stream>>>(Wf, Tf, Wb, Tb, wp2s, ws2p, fri,
                                         Xprev, Sprev, Pprev, Uprev, PSprev,
                                         S, P, Unew, PSnew,
                                         xs + (size_t)t * BN, out,
                                         (t == NSTEPS - 1) ? 1 : 0);
  }
}